// Round 6
// baseline (421.445 us; speedup 1.0000x reference)
//
#include <hip/hip_runtime.h>
#include <stdint.h>

#define RR 32
#define R3 32768
#define NB 8
#define NCH 64
#define NP 16384

typedef unsigned short u16;
typedef uint32_t u32;
typedef __attribute__((ext_vector_type(8))) short bf8;
typedef __attribute__((ext_vector_type(4))) float f4;
typedef __attribute__((ext_vector_type(16))) float f16x;

#define MFMA(a,b,c)   __builtin_amdgcn_mfma_f32_16x16x32_bf16(a,b,c,0,0,0)
#define MFMA32(a,b,c) __builtin_amdgcn_mfma_f32_32x32x16_bf16(a,b,c,0,0,0)

__device__ __forceinline__ float bf2f(u16 v){
  union { u32 u; float f; } x; x.u = ((u32)v) << 16; return x.f;
}
__device__ __forceinline__ float u2f(u32 u){
  union { u32 u; float f; } x; x.u = u; return x.f;
}
__device__ __forceinline__ u16 f2bf(float f){
  union { float f; u32 u; } x; x.f = f;
  u32 r = x.u + 0x7fffu + ((x.u >> 16) & 1u);
  return (u16)(r >> 16);
}
__device__ __forceinline__ float ldf(const void* p, size_t i, int isbf){
  return isbf ? bf2f(((const u16*)p)[i]) : ((const float*)p)[i];
}

// ---------------- workspace layout ----------------
#define OFF_GRID  0ull
#define OFF_BUF1  33554432ull
#define OFF_FT    33554432ull
#define OFF_P     67108864ull
#define OFF_CNT   83886080ull     // int [8][32768]           (zeroed)
#define OFF_SMALL 84934656ull     // 2048 B                   (zeroed)
#define OFF_STAT  84936704ull     // 3 x 1024 fp32 spread     (zeroed)
#define OFF_OFFS  84948992ull
#define OFF_NC    85997568ull
#define OFF_VIDX  87570432ull
#define OFF_SORT  88094720ull
#define OFF_WF1   88619008ull
#define OFF_WF2   88840192ull
#define OFF_WFP   89061376ull
#define WS_NEED   89069568ull
#define ZOFF      OFF_CNT
#define ZBYTES    1062912ull      // cnt + small + stat in one memset

__global__ void k_dtype(const uint32_t* __restrict__ gamma_raw, int* __restrict__ flag){
  if (threadIdx.x == 0) *flag = (gamma_raw[0] == 0x3F800000u) ? 0 : 1;
}

__global__ void k_coordstats(const void* __restrict__ coords, float* __restrict__ small,
                             const int* __restrict__ dflag){
  int b = blockIdx.x; int tid = threadIdx.x;
  int isbf = *dflag;
  __shared__ float red[1024];
  size_t cb = (size_t)b*3*NP;
  float sx=0.f, sy=0.f, sz=0.f;
  for (int n = tid; n < NP; n += 1024){
    sx += ldf(coords, cb+n, isbf);
    sy += ldf(coords, cb+NP+n, isbf);
    sz += ldf(coords, cb+2*NP+n, isbf);
  }
  float m[3]; float* sums[3] = {&sx,&sy,&sz};
  for (int a = 0; a < 3; a++){
    red[tid] = *sums[a]; __syncthreads();
    for (int s = 512; s > 0; s >>= 1){ if (tid < s) red[tid] += red[tid+s]; __syncthreads(); }
    m[a] = red[0] * (1.0f/NP); __syncthreads();
  }
  float vm = 0.f;
  for (int n = tid; n < NP; n += 1024){
    float cx = ldf(coords, cb+n, isbf)      - m[0];
    float cy = ldf(coords, cb+NP+n, isbf)   - m[1];
    float cz = ldf(coords, cb+2*NP+n, isbf) - m[2];
    vm = fmaxf(vm, sqrtf(cx*cx + cy*cy + cz*cz));
  }
  red[tid] = vm; __syncthreads();
  for (int s = 512; s > 0; s >>= 1){ if (tid < s) red[tid] = fmaxf(red[tid], red[tid+s]); __syncthreads(); }
  if (tid == 0){
    small[384 + b*4 + 0] = m[0];
    small[384 + b*4 + 1] = m[1];
    small[384 + b*4 + 2] = m[2];
    small[384 + b*4 + 3] = 1.0f / (2.0f*red[0] + 1e-6f);
  }
}

__global__ void k_pointprep(const void* __restrict__ coords, const float* __restrict__ small,
                            float* __restrict__ nc, int* __restrict__ vidx, int* __restrict__ cnt,
                            const int* __restrict__ dflag){
  int g = blockIdx.x*256 + threadIdx.x;
  int isbf = *dflag;
  int b = g >> 14; int n = g & (NP-1);
  float mx = small[384+b*4+0], my = small[384+b*4+1], mz = small[384+b*4+2], sc = small[384+b*4+3];
  size_t cb = (size_t)b*3*NP;
  float nx = ((ldf(coords, cb+n, isbf)      - mx)*sc + 0.5f) * 32.0f;
  float ny = ((ldf(coords, cb+NP+n, isbf)   - my)*sc + 0.5f) * 32.0f;
  float nz = ((ldf(coords, cb+2*NP+n, isbf) - mz)*sc + 0.5f) * 32.0f;
  nx = fminf(fmaxf(nx, 0.f), 31.f);
  ny = fminf(fmaxf(ny, 0.f), 31.f);
  nz = fminf(fmaxf(nz, 0.f), 31.f);
  nc[(b*3+0)*NP + n] = nx; nc[(b*3+1)*NP + n] = ny; nc[(b*3+2)*NP + n] = nz;
  int vx = (int)rintf(nx), vy = (int)rintf(ny), vz = (int)rintf(nz);
  int flat = (vx*32 + vy)*32 + vz;
  vidx[g] = flat;
  atomicAdd(&cnt[b*R3 + flat], 1);
}

__global__ void k_scan(const int* __restrict__ cnt, int* __restrict__ off){
  __shared__ int part[1024];
  int b = blockIdx.x, tid = threadIdx.x;
  int base = b*R3 + tid*32;
  int s = 0;
  for (int i = 0; i < 32; i++) s += cnt[base + i];
  part[tid] = s; __syncthreads();
  for (int st = 1; st < 1024; st <<= 1){
    int v = (tid >= st) ? part[tid - st] : 0;
    __syncthreads();
    part[tid] += v;
    __syncthreads();
  }
  int run = (tid == 0) ? 0 : part[tid - 1];
  for (int i = 0; i < 32; i++){ off[base + i] = run; run += cnt[base + i]; }
}

__global__ void k_sortpts(const int* __restrict__ vidx, int* __restrict__ off, int* __restrict__ sorted){
  int g = blockIdx.x*256 + threadIdx.x;
  int b = g >> 14; int n = g & (NP-1);
  int v = vidx[g];
  int slot = atomicAdd(&off[b*R3 + v], 1);
  sorted[b*NP + slot] = n;
}

// 16 voxels per wave: coalesced cnt/off loads (lanes 0-15), one coalesced
// prefetch of up to 64 sorted point indices, shfl-distributed; 2-way unrolled
// fT accumulation for load overlap. (R4->R5: 73us -> off the top-5.)
__global__ __launch_bounds__(256) void k_voxsum(const u16* __restrict__ fT, const int* __restrict__ sorted,
                         const int* __restrict__ cnt, const int* __restrict__ off,
                         u16* __restrict__ grid){
  int wid = blockIdx.x*4 + (threadIdx.x >> 6);   // NB*R3/16 = 16384 wids
  int lane = threadIdx.x & 63;
  int b = wid >> 11;                             // R3/16 = 2048 groups/batch
  int v0 = (wid & 2047) << 4;
  int base = b*R3 + v0;
  int c = 0, e = 0;
  if (lane < 16){ c = cnt[base + lane]; e = off[base + lane]; }
  int start = __shfl(e - c, 0);                  // absolute start of group range
  int total = __shfl(e, 15) - start;
  const int* sb = sorted + (size_t)b*NP;
  int sp = 0;
  if (lane < total) sp = sb[start + lane];
  #pragma unroll
  for (int i = 0; i < 16; i++){
    int ci = __shfl(c, i);
    int rel = __shfl(e, i) - ci - start;         // group-relative start of voxel i
    float a0 = 0.f, a1 = 0.f;
    int j = 0;
    for (; j + 1 < ci; j += 2){
      int k0 = rel + j, k1 = k0 + 1;
      int n0 = (k0 < 64) ? __shfl(sp, k0) : sb[start + k0];
      int n1 = (k1 < 64) ? __shfl(sp, k1) : sb[start + k1];
      a0 += bf2f(fT[((size_t)(b*NP + n0))*64 + lane]);
      a1 += bf2f(fT[((size_t)(b*NP + n1))*64 + lane]);
    }
    if (j < ci){
      int k0 = rel + j;
      int n0 = (k0 < 64) ? __shfl(sp, k0) : sb[start + k0];
      a0 += bf2f(fT[((size_t)(b*NP + n0))*64 + lane]);
    }
    float acc = a0 + a1;
    grid[((size_t)(base + i))*64 + lane] = f2bf(acc / (float)max(ci, 1));
  }
}

// weight pack for 16x16x32 path (point-branch GEMM)
__global__ void k_wprep(const void* __restrict__ w, u16* __restrict__ wfrag, const int* __restrict__ dflag){
  int idx = blockIdx.x; int lane = threadIdx.x;
  int isbf = *dflag;
  int ntl = idx & 3; int kk = (idx >> 2) & 1; int tap = idx >> 3;
  int lh = lane & 15, quad = lane >> 4;
  int n = ntl*16 + lh;
  u16* dst = wfrag + ((size_t)idx*64 + lane)*8;
  for (int j = 0; j < 8; j++){
    int k = kk*32 + quad*8 + j;
    dst[j] = f2bf(ldf(w, (size_t)(tap*64 + k)*64 + n, isbf));
  }
}

// weight pack for 32x32x16 conv path.
// frag idx = (tap*4 + ks)*2 + nh ; B-frag layout: n = lane&31 (cout within 32),
// k = (lane>>5)*8 + j, cin = ks*16 + k.  216 frags x 1 KB = 216 KB (same footprint).
__global__ void k_wprep32(const void* __restrict__ w, u16* __restrict__ wfrag, const int* __restrict__ dflag){
  int idx = blockIdx.x; int lane = threadIdx.x;
  int isbf = *dflag;
  int nh = idx & 1; int ks = (idx >> 1) & 3; int tap = idx >> 3;
  int n = nh*32 + (lane & 31);
  int khalf = lane >> 5;
  u16* dst = wfrag + ((size_t)idx*64 + lane)*8;
  for (int j = 0; j < 8; j++){
    int cin = ks*16 + khalf*8 + j;
    dst[j] = f2bf(ldf(w, (size_t)(tap*64 + cin)*64 + n, isbf));
  }
}

// ---------------- BN helper on spread stats ----------------
__device__ __forceinline__ void bn_params(const float* __restrict__ spread, int c, float invM,
                                          float* mean, float* rs){
  float su = 0.f, sq = 0.f;
  #pragma unroll
  for (int i = 0; i < 8; i++){ su += spread[i*128 + c]; sq += spread[i*128 + 64 + c]; }
  float m = su * invM;
  *mean = m;
  *rs = rsqrtf(sq*invM - m*m + 1e-4f);
}

// ---------------- conv3d 3x3x3, 32x32x16 MFMA, zero-padded LDS, fenced pipeline ----------------
// R6: wave = (usel, vsel) owns ONE (u,v) output row and ALL 64 couts
// (acc0 = couts 0-31, acc1 = 32-63). LDS A-reads per tap drop 8 -> 4 (no more
// nh-duplication: R5 PMC showed LDS-read pipe = ~66% of kernel cycles);
// weight loads per tap rise 4 -> 8 but all 4 waves fetch the SAME addresses in
// near-lockstep -> L1 serves duplicates, unique L2 traffic/block unchanged.
// Pipeline: W-ring 3 banks 2 taps ahead (vmcnt(16)); A 2 banks 1 tap ahead
// (lgkmcnt(4)); sched_barrier(0) fences (R4-proven structure).
#define ISSUE_W8(BANK, TAP) do { \
  _Pragma("unroll") \
  for (int k_ = 0; k_ < 8; k_++) \
    BANK[k_] = *(const bf8*)(wstream + (size_t)((TAP)*8 + k_)*512); \
} while(0)

#define ISSUE_A4(B0, TAP) do { \
  const int t_ = (TAP); \
  const int dwi_ = t_ % 3, dvi_ = (t_/3) % 3, dui_ = t_/9; \
  const u16* rp_ = &lds_in[((dui_ + usel)*4 + vsel + dvi_)*2176]; \
  const int wp_ = mlane + dwi_; \
  const int wb_ = wp_*64, wx_ = wp_ & 7; \
  _Pragma("unroll") \
  for (int ks_ = 0; ks_ < 4; ks_++){ \
    const int off_ = wb_ + ((((ks_*2) + khalf) ^ wx_) << 3); \
    B0[ks_] = *(const bf8*)(rp_ + off_); \
  } \
} while(0)

#define CONSUME(BW, B0) do { \
  _Pragma("unroll") \
  for (int ks_ = 0; ks_ < 4; ks_++){ \
    acc0 = MFMA32(B0[ks_], BW[ks_*2+0], acc0); \
    acc1 = MFMA32(B0[ks_], BW[ks_*2+1], acc1); \
  } \
} while(0)

template<int BN>
__global__ __launch_bounds__(256, 2) void k_conv_t(const u16* __restrict__ in, const u16* __restrict__ wfrag,
                                                   u16* __restrict__ out, const float* __restrict__ spread,
                                                   const void* __restrict__ gamma, const void* __restrict__ beta,
                                                   const int* __restrict__ dflag){
  __shared__ u16 lds_in[16*2176];
  __shared__ float bnA[64], bnB[64];
  int bx = blockIdx.x;
  int b = bx >> 8; int r = bx & 255;
  int u0 = (r >> 4) * 2; int v0 = (r & 15) * 2;
  int tid = threadIdx.x, wv = tid >> 6, lane = tid & 63;

  if constexpr (BN){
    if (tid < 64){
      int isbf = *dflag;
      float mean, rs;
      bn_params(spread, tid, 1.0f/(NB*R3), &mean, &rs);
      float ga = ldf(gamma, tid, isbf), be = ldf(beta, tid, isbf);
      float A = ga*rs;
      bnA[tid] = A; bnB[tid] = be - mean*A;
    }
    __syncthreads();
  }

  uint4 zz; zz.x = 0; zz.y = 0; zz.z = 0; zz.w = 0;
  for (int ri = wv; ri < 16; ri += 4){
    int u2 = u0 + (ri >> 2) - 1;
    int v2 = v0 + (ri & 3) - 1;
    uint4* dstrow = (uint4*)&lds_in[ri*2176];
    if ((unsigned)u2 > 31u || (unsigned)v2 > 31u){
      for (int i = lane; i < 272; i += 64) dstrow[i] = zz;
      continue;
    }
    const uint4* src = (const uint4*)(in + ((size_t)(b*R3 + (u2*32 + v2)*32))*64);
    if (lane < 8) dstrow[lane] = zz;
    else if (lane < 16) dstrow[264 + (lane & 7)] = zz;
    #pragma unroll
    for (int ch = 0; ch < 4; ch++){
      int idx = ch*64 + lane;
      int w = idx >> 3, cc = idx & 7;
      uint4 v = src[idx];
      if constexpr (BN){
        u32 in4[4] = {v.x, v.y, v.z, v.w};
        u32 o4[4];
        #pragma unroll
        for (int k = 0; k < 4; k++){
          int c = cc*8 + 2*k;
          float lo = u2f(in4[k] << 16);
          float hi = u2f(in4[k] & 0xFFFF0000u);
          lo = bnA[c]*lo + bnB[c];     lo = (lo >= 0.f) ? lo : 0.1f*lo;
          hi = bnA[c+1]*hi + bnB[c+1]; hi = (hi >= 0.f) ? hi : 0.1f*hi;
          o4[k] = (u32)f2bf(lo) | ((u32)f2bf(hi) << 16);
        }
        v.x = o4[0]; v.y = o4[1]; v.z = o4[2]; v.w = o4[3];
      }
      int wp = w + 1;
      dstrow[wp*8 + (cc ^ (wp & 7))] = v;
    }
  }
  __syncthreads();

  int usel = wv >> 1, vsel = wv & 1;
  int u_i = u0 + usel, v_i = v0 + vsel;
  int mlane = lane & 31;          // output w position (M dim)
  int khalf = lane >> 5;          // k-half within a K=16 step
  f16x acc0, acc1;                // couts 0-31, 32-63
  #pragma unroll
  for (int i = 0; i < 16; i++){ acc0[i] = 0.f; acc1[i] = 0.f; }

  const u16* wstream = wfrag + (size_t)lane*8;  // + (tap*8 + ks*2+nh)*512 per frag

  bf8 W0[8], W1[8], W2[8];        // weight ring, 2 taps ahead (8 frags/tap)
  bf8 Aa[4], Ab[4];               // A double-bank, 1 tap ahead (4 frags/tap)

  ISSUE_W8(W0, 0);
  ISSUE_W8(W1, 1);
  ISSUE_A4(Aa, 0);

  #pragma unroll
  for (int tap = 0; tap < 27; ++tap){
    const int pf = tap + 2;
    if (pf < 27){
      if (pf % 3 == 0)      ISSUE_W8(W0, pf);
      else if (pf % 3 == 1) ISSUE_W8(W1, pf);
      else                  ISSUE_W8(W2, pf);
    }
    if (tap + 1 < 27){
      if ((tap + 1) & 1) ISSUE_A4(Ab, tap + 1);
      else               ISSUE_A4(Aa, tap + 1);
    }
    __builtin_amdgcn_sched_barrier(0);
    if (tap < 25)       asm volatile("s_waitcnt vmcnt(16) lgkmcnt(4)");
    else if (tap == 25) asm volatile("s_waitcnt vmcnt(8) lgkmcnt(4)");
    else                asm volatile("s_waitcnt vmcnt(0) lgkmcnt(0)");
    __builtin_amdgcn_sched_barrier(0);
    const int wsel = tap % 3, asel = tap & 1;
    if (wsel == 0){ if (asel == 0) CONSUME(W0, Aa); else CONSUME(W0, Ab); }
    else if (wsel == 1){ if (asel == 0) CONSUME(W1, Aa); else CONSUME(W1, Ab); }
    else              { if (asel == 0) CONSUME(W2, Aa); else CONSUME(W2, Ab); }
  }

  // C/D layout 32x32: col = lane&31 (cout), row = (reg&3) + 8*(reg>>2) + 4*(lane>>5)
  int rbase = 4*khalf;
  size_t base0 = ((size_t)(b*R3 + (u_i*32 + v_i)*32))*64;
  #pragma unroll
  for (int reg = 0; reg < 16; reg++){
    int row = (reg & 3) + 8*(reg >> 2) + rbase;       // w position
    out[base0 + (size_t)row*64 + mlane]      = f2bf(acc0[reg]);
    out[base0 + (size_t)row*64 + 32 + mlane] = f2bf(acc1[reg]);
  }
}

// ---------------- fast channel stats ----------------
__global__ __launch_bounds__(256) void k_stats2(const u16* __restrict__ buf, float* __restrict__ spread, int M){
  __shared__ float sred[4*128];
  int tid = threadIdx.x, bx = blockIdx.x;
  int wv = tid >> 6, lane = tid & 63;
  int sub = lane & 7;
  int g = bx*256 + tid;
  float s[8], s2[8];
  #pragma unroll
  for (int j = 0; j < 8; j++){ s[j] = 0.f; s2[j] = 0.f; }
  const uint4* p4 = (const uint4*)buf;
  size_t total = (size_t)M * 8;
  for (size_t f = g; f < total; f += 262144){
    uint4 v = p4[f];
    u32 ws_[4] = {v.x, v.y, v.z, v.w};
    #pragma unroll
    for (int k = 0; k < 4; k++){
      float lo = u2f(ws_[k] << 16);
      float hi = u2f(ws_[k] & 0xFFFF0000u);
      s[2*k]   += lo; s2[2*k]   += lo*lo;
      s[2*k+1] += hi; s2[2*k+1] += hi*hi;
    }
  }
  #pragma unroll
  for (int j = 0; j < 8; j++){
    #pragma unroll
    for (int m = 8; m <= 32; m <<= 1){
      s[j]  += __shfl_xor(s[j],  m);
      s2[j] += __shfl_xor(s2[j], m);
    }
  }
  if (lane < 8){
    #pragma unroll
    for (int j = 0; j < 8; j++){
      sred[wv*128 + sub*8 + j]      = s[j];
      sred[wv*128 + 64 + sub*8 + j] = s2[j];
    }
  }
  __syncthreads();
  if (tid < 128){
    float t = sred[tid] + sred[128+tid] + sred[256+tid] + sred[384+tid];
    atomicAdd(&spread[(bx & 7)*128 + tid], t);
  }
}

__global__ void k_ftrans(const void* __restrict__ feat, u16* __restrict__ fT, const int* __restrict__ dflag){
  __shared__ u16 t[64*65];
  int bx = blockIdx.x;
  int isbf = *dflag;
  int b = bx >> 8; int n0 = (bx & 255) * 64;
  int tid = threadIdx.x;
  int nl = tid & 63; int cq = tid >> 6;
  for (int cp = 0; cp < 16; cp++){
    int c = cq + cp*4;
    t[c*65 + nl] = f2bf(ldf(feat, ((size_t)(b*NCH + c))*NP + n0 + nl, isbf));
  }
  __syncthreads();
  for (int np2 = 0; np2 < 16; np2++){
    int n = np2*4 + cq; int c = nl;
    fT[((size_t)(b*NP + n0 + n))*64 + c] = t[c*65 + n];
  }
}

__global__ void k_pgemm(const u16* __restrict__ fT, const u16* __restrict__ wfp, u16* __restrict__ p){
  __shared__ u16 As[128*64];
  int bx = blockIdx.x;
  size_t row0 = (size_t)bx * 128;
  int tid = threadIdx.x, wv = tid >> 6, lane = tid & 63;
  const uint4* src = (const uint4*)(fT + row0*64);
  uint4* dst = (uint4*)As;
  for (int i = tid; i < 1024; i += 256) dst[i] = src[i];
  __syncthreads();
  int lh = lane & 15, quad = lane >> 4;
  f4 z4 = {0.f,0.f,0.f,0.f};
  f4 acc[2][4];
  for (int i = 0; i < 2; i++) for (int j = 0; j < 4; j++) acc[i][j] = z4;
  const u16* ap = &As[(wv*32)*64];
  #pragma unroll
  for (int kk = 0; kk < 2; kk++){
    bf8 a0 = *(const bf8*)(ap + lh*64 + kk*32 + quad*8);
    bf8 a1 = *(const bf8*)(ap + (16+lh)*64 + kk*32 + quad*8);
    #pragma unroll
    for (int ntl = 0; ntl < 4; ntl++){
      bf8 bf = *(const bf8*)(wfp + ((size_t)(kk*4 + ntl)*64 + lane)*8);
      acc[0][ntl] = MFMA(a0, bf, acc[0][ntl]);
      acc[1][ntl] = MFMA(a1, bf, acc[1][ntl]);
    }
  }
  #pragma unroll
  for (int mt = 0; mt < 2; mt++)
    for (int ntl = 0; ntl < 4; ntl++)
      for (int reg = 0; reg < 4; reg++){
        int rr = wv*32 + mt*16 + quad*4 + reg;
        p[(row0 + rr)*64 + ntl*16 + lh] = f2bf(acc[mt][ntl][reg]);
      }
}

// devox with BN2+LeakyReLU fused on the grid gathers + point-branch BN
__global__ void k_devox(const u16* __restrict__ grid, const u16* __restrict__ p,
                        const float* __restrict__ stP, const float* __restrict__ st2,
                        const void* __restrict__ pfg, const void* __restrict__ pfb,
                        const void* __restrict__ g2, const void* __restrict__ b2,
                        const float* __restrict__ nc, void* __restrict__ out0,
                        const int* __restrict__ dflag){
  __shared__ float t[64*65];
  int bx = blockIdx.x;
  int isbf = *dflag;
  int b = bx >> 8; int n0 = (bx & 255) * 64;
  int tid = threadIdx.x, wv = tid >> 6, lane = tid & 63;
  int c = lane;
  float meanP, rsP;
  bn_params(stP, c, 1.0f/(NB*NP), &meanP, &rsP);
  float gaP = ldf(pfg, c, isbf), beP = ldf(pfb, c, isbf);
  float mean2, rs2;
  bn_params(st2, c, 1.0f/(NB*R3), &mean2, &rs2);
  float ga2 = ldf(g2, c, isbf), be2 = ldf(b2, c, isbf);
  float A2 = ga2*rs2, B2 = be2 - mean2*A2;
  for (int pt = wv; pt < 64; pt += 4){
    int n = n0 + pt;
    float nx = nc[(b*3+0)*NP + n];
    float ny = nc[(b*3+1)*NP + n];
    float nz = nc[(b*3+2)*NP + n];
    float x0f = floorf(nx), y0f = floorf(ny), z0f = floorf(nz);
    int x0 = (int)x0f, y0 = (int)y0f, z0 = (int)z0f;
    float fx = nx - x0f, fy = ny - y0f, fz = nz - z0f;
    int x1 = min(x0+1,31), y1 = min(y0+1,31), z1 = min(z0+1,31);
    float acc = 0.f;
    #pragma unroll
    for (int k = 0; k < 8; k++){
      int dx = k >> 2, dy = (k >> 1) & 1, dz = k & 1;
      int xs = dx ? x1 : x0, ys = dy ? y1 : y0, zs = dz ? z1 : z0;
      float wgt = (dx ? fx : 1.f-fx)*(dy ? fy : 1.f-fy)*(dz ? fz : 1.f-fz);
      float gv = bf2f(grid[((size_t)(b*R3 + (xs*32+ys)*32 + zs))*64 + c]);
      gv = A2*gv + B2;
      gv = (gv >= 0.f) ? gv : 0.1f*gv;
      acc += wgt * gv;
    }
    float pv = bf2f(p[((size_t)(b*NP + n))*64 + c]);
    float y = gaP*(pv - meanP)*rsP + beP;
    y = (y >= 0.f) ? y : 0.1f*y;
    t[pt*65 + c] = acc + y;
  }
  __syncthreads();
  for (int cp = 0; cp < 16; cp++){
    int co = wv + cp*4;
    size_t oi = ((size_t)(b*NCH + co))*NP + n0 + lane;
    float val = t[lane*65 + co];
    if (isbf) ((u16*)out0)[oi] = f2bf(val);
    else      ((float*)out0)[oi] = val;
  }
}

__global__ void k_copycoords(const void* __restrict__ coords, void* __restrict__ out0,
                             const int* __restrict__ dflag){
  int g = blockIdx.x*256 + threadIdx.x;
  int isbf = *dflag;
  size_t oi = (size_t)NB*NCH*NP + g;
  if (isbf) ((u16*)out0)[oi]   = ((const u16*)coords)[g];
  else      ((float*)out0)[oi] = ((const float*)coords)[g];
}

extern "C" void kernel_launch(void* const* d_in, const int* in_sizes, int n_in,
                              void* d_out, int out_size, void* d_ws, size_t ws_size,
                              hipStream_t stream){
  if (ws_size < WS_NEED) return;

  const void* feat   = d_in[0];
  const void* coords = d_in[1];
  const void* w1     = d_in[2];
  const void* g1     = d_in[4];
  const void* b1     = d_in[5];
  const void* w2     = d_in[6];
  const void* g2     = d_in[8];
  const void* b2     = d_in[9];
  const void* pw     = d_in[10];
  const void* pg     = d_in[12];
  const void* pb     = d_in[13];

  char* ws = (char*)d_ws;
  u16*   gridv = (u16*)(ws + OFF_GRID);
  u16*   buf1  = (u16*)(ws + OFF_BUF1);
  u16*   fT    = (u16*)(ws + OFF_FT);     // overlays buf1; dead before conv1 writes
  u16*   p     = (u16*)(ws + OFF_P);
  int*   cnt   = (int*)(ws + OFF_CNT);
  float* small = (float*)(ws + OFF_SMALL);
  int*   dflag = (int*)(small + 448);
  float* stat  = (float*)(ws + OFF_STAT); // [3][1024] spread: conv1 | conv2 | point
  int*   offs  = (int*)(ws + OFF_OFFS);
  float* nc    = (float*)(ws + OFF_NC);
  int*   vidx  = (int*)(ws + OFF_VIDX);
  int*   sorted= (int*)(ws + OFF_SORT);
  u16*   wf1   = (u16*)(ws + OFF_WF1);
  u16*   wf2   = (u16*)(ws + OFF_WF2);
  u16*   wfp   = (u16*)(ws + OFF_WFP);

  hipMemsetAsync(ws + ZOFF, 0, ZBYTES, stream);
  k_dtype<<<1, 64, 0, stream>>>((const uint32_t*)g1, dflag);

  k_wprep32<<<27*8, 64, 0, stream>>>(w1, wf1, dflag);
  k_wprep32<<<27*8, 64, 0, stream>>>(w2, wf2, dflag);
  k_wprep<<<8, 64, 0, stream>>>(pw, wfp, dflag);

  k_coordstats<<<NB, 1024, 0, stream>>>(coords, small, dflag);
  k_pointprep<<<NB*NP/256, 256, 0, stream>>>(coords, small, nc, vidx, cnt, dflag);
  k_scan<<<NB, 1024, 0, stream>>>(cnt, offs);
  k_sortpts<<<NB*NP/256, 256, 0, stream>>>(vidx, offs, sorted);

  k_ftrans<<<NB*NP/64, 256, 0, stream>>>(feat, fT, dflag);
  k_voxsum<<<NB*R3/64, 256, 0, stream>>>(fT, sorted, cnt, offs, gridv);
  k_pgemm<<<NB*NP/128, 256, 0, stream>>>(fT, wfp, p);
  k_stats2<<<1024, 256, 0, stream>>>(p, stat + 2048, NB*NP);

  k_conv_t<0><<<NB*256, 256, 0, stream>>>(gridv, wf1, buf1, nullptr, nullptr, nullptr, nullptr);
  k_stats2<<<1024, 256, 0, stream>>>(buf1, stat + 0, NB*R3);

  k_conv_t<1><<<NB*256, 256, 0, stream>>>(buf1, wf2, gridv, stat + 0, g1, b1, dflag);
  k_stats2<<<1024, 256, 0, stream>>>(gridv, stat + 1024, NB*R3);

  k_devox<<<NB*NP/64, 256, 0, stream>>>(gridv, p, stat + 2048, stat + 1024,
                                        pg, pb, g2, b2, nc, d_out, dflag);
  k_copycoords<<<NB*3*NP/256, 256, 0, stream>>>(coords, d_out, dflag);
}

// Round 7
// 395.935 us; speedup vs baseline: 1.0644x; 1.0644x over previous
//
#include <hip/hip_runtime.h>
#include <stdint.h>

#define RR 32
#define R3 32768
#define NB 8
#define NCH 64
#define NP 16384

typedef unsigned short u16;
typedef uint32_t u32;
typedef __attribute__((ext_vector_type(8))) short bf8;
typedef __attribute__((ext_vector_type(4))) float f4;
typedef __attribute__((ext_vector_type(16))) float f16x;

#define MFMA(a,b,c)   __builtin_amdgcn_mfma_f32_16x16x32_bf16(a,b,c,0,0,0)
#define MFMA32(a,b,c) __builtin_amdgcn_mfma_f32_32x32x16_bf16(a,b,c,0,0,0)

__device__ __forceinline__ float bf2f(u16 v){
  union { u32 u; float f; } x; x.u = ((u32)v) << 16; return x.f;
}
__device__ __forceinline__ float u2f(u32 u){
  union { u32 u; float f; } x; x.u = u; return x.f;
}
__device__ __forceinline__ u16 f2bf(float f){
  union { float f; u32 u; } x; x.f = f;
  u32 r = x.u + 0x7fffu + ((x.u >> 16) & 1u);
  return (u16)(r >> 16);
}
__device__ __forceinline__ float ldf(const void* p, size_t i, int isbf){
  return isbf ? bf2f(((const u16*)p)[i]) : ((const float*)p)[i];
}

// ---------------- workspace layout ----------------
#define OFF_GRID  0ull
#define OFF_BUF1  33554432ull
#define OFF_FT    33554432ull
#define OFF_P     67108864ull
#define OFF_CNT   83886080ull     // int [8][32768]           (zeroed)
#define OFF_SMALL 84934656ull     // 2048 B                   (zeroed)
#define OFF_STAT  84936704ull     // 3 x 1024 fp32 spread     (zeroed)
#define OFF_OFFS  84948992ull
#define OFF_NC    85997568ull
#define OFF_VIDX  87570432ull
#define OFF_SORT  88094720ull
#define OFF_WF1   88619008ull
#define OFF_WF2   88840192ull
#define OFF_WFP   89061376ull
#define WS_NEED   89069568ull
#define ZOFF      OFF_CNT
#define ZBYTES    1062912ull      // cnt + small + stat in one memset

__global__ void k_dtype(const uint32_t* __restrict__ gamma_raw, int* __restrict__ flag){
  if (threadIdx.x == 0) *flag = (gamma_raw[0] == 0x3F800000u) ? 0 : 1;
}

__global__ void k_coordstats(const void* __restrict__ coords, float* __restrict__ small,
                             const int* __restrict__ dflag){
  int b = blockIdx.x; int tid = threadIdx.x;
  int isbf = *dflag;
  __shared__ float red[1024];
  size_t cb = (size_t)b*3*NP;
  float sx=0.f, sy=0.f, sz=0.f;
  for (int n = tid; n < NP; n += 1024){
    sx += ldf(coords, cb+n, isbf);
    sy += ldf(coords, cb+NP+n, isbf);
    sz += ldf(coords, cb+2*NP+n, isbf);
  }
  float m[3]; float* sums[3] = {&sx,&sy,&sz};
  for (int a = 0; a < 3; a++){
    red[tid] = *sums[a]; __syncthreads();
    for (int s = 512; s > 0; s >>= 1){ if (tid < s) red[tid] += red[tid+s]; __syncthreads(); }
    m[a] = red[0] * (1.0f/NP); __syncthreads();
  }
  float vm = 0.f;
  for (int n = tid; n < NP; n += 1024){
    float cx = ldf(coords, cb+n, isbf)      - m[0];
    float cy = ldf(coords, cb+NP+n, isbf)   - m[1];
    float cz = ldf(coords, cb+2*NP+n, isbf) - m[2];
    vm = fmaxf(vm, sqrtf(cx*cx + cy*cy + cz*cz));
  }
  red[tid] = vm; __syncthreads();
  for (int s = 512; s > 0; s >>= 1){ if (tid < s) red[tid] = fmaxf(red[tid], red[tid+s]); __syncthreads(); }
  if (tid == 0){
    small[384 + b*4 + 0] = m[0];
    small[384 + b*4 + 1] = m[1];
    small[384 + b*4 + 2] = m[2];
    small[384 + b*4 + 3] = 1.0f / (2.0f*red[0] + 1e-6f);
  }
}

__global__ void k_pointprep(const void* __restrict__ coords, const float* __restrict__ small,
                            float* __restrict__ nc, int* __restrict__ vidx, int* __restrict__ cnt,
                            const int* __restrict__ dflag){
  int g = blockIdx.x*256 + threadIdx.x;
  int isbf = *dflag;
  int b = g >> 14; int n = g & (NP-1);
  float mx = small[384+b*4+0], my = small[384+b*4+1], mz = small[384+b*4+2], sc = small[384+b*4+3];
  size_t cb = (size_t)b*3*NP;
  float nx = ((ldf(coords, cb+n, isbf)      - mx)*sc + 0.5f) * 32.0f;
  float ny = ((ldf(coords, cb+NP+n, isbf)   - my)*sc + 0.5f) * 32.0f;
  float nz = ((ldf(coords, cb+2*NP+n, isbf) - mz)*sc + 0.5f) * 32.0f;
  nx = fminf(fmaxf(nx, 0.f), 31.f);
  ny = fminf(fmaxf(ny, 0.f), 31.f);
  nz = fminf(fmaxf(nz, 0.f), 31.f);
  nc[(b*3+0)*NP + n] = nx; nc[(b*3+1)*NP + n] = ny; nc[(b*3+2)*NP + n] = nz;
  int vx = (int)rintf(nx), vy = (int)rintf(ny), vz = (int)rintf(nz);
  int flat = (vx*32 + vy)*32 + vz;
  vidx[g] = flat;
  atomicAdd(&cnt[b*R3 + flat], 1);
}

__global__ void k_scan(const int* __restrict__ cnt, int* __restrict__ off){
  __shared__ int part[1024];
  int b = blockIdx.x, tid = threadIdx.x;
  int base = b*R3 + tid*32;
  int s = 0;
  for (int i = 0; i < 32; i++) s += cnt[base + i];
  part[tid] = s; __syncthreads();
  for (int st = 1; st < 1024; st <<= 1){
    int v = (tid >= st) ? part[tid - st] : 0;
    __syncthreads();
    part[tid] += v;
    __syncthreads();
  }
  int run = (tid == 0) ? 0 : part[tid - 1];
  for (int i = 0; i < 32; i++){ off[base + i] = run; run += cnt[base + i]; }
}

__global__ void k_sortpts(const int* __restrict__ vidx, int* __restrict__ off, int* __restrict__ sorted){
  int g = blockIdx.x*256 + threadIdx.x;
  int b = g >> 14; int n = g & (NP-1);
  int v = vidx[g];
  int slot = atomicAdd(&off[b*R3 + v], 1);
  sorted[b*NP + slot] = n;
}

// 16 voxels per wave: coalesced cnt/off loads (lanes 0-15), one coalesced
// prefetch of up to 64 sorted point indices, shfl-distributed; 2-way unrolled
// fT accumulation for load overlap. (R4->R5: 73us -> off the top-5.)
__global__ __launch_bounds__(256) void k_voxsum(const u16* __restrict__ fT, const int* __restrict__ sorted,
                         const int* __restrict__ cnt, const int* __restrict__ off,
                         u16* __restrict__ grid){
  int wid = blockIdx.x*4 + (threadIdx.x >> 6);   // NB*R3/16 = 16384 wids
  int lane = threadIdx.x & 63;
  int b = wid >> 11;                             // R3/16 = 2048 groups/batch
  int v0 = (wid & 2047) << 4;
  int base = b*R3 + v0;
  int c = 0, e = 0;
  if (lane < 16){ c = cnt[base + lane]; e = off[base + lane]; }
  int start = __shfl(e - c, 0);                  // absolute start of group range
  int total = __shfl(e, 15) - start;
  const int* sb = sorted + (size_t)b*NP;
  int sp = 0;
  if (lane < total) sp = sb[start + lane];
  #pragma unroll
  for (int i = 0; i < 16; i++){
    int ci = __shfl(c, i);
    int rel = __shfl(e, i) - ci - start;         // group-relative start of voxel i
    float a0 = 0.f, a1 = 0.f;
    int j = 0;
    for (; j + 1 < ci; j += 2){
      int k0 = rel + j, k1 = k0 + 1;
      int n0 = (k0 < 64) ? __shfl(sp, k0) : sb[start + k0];
      int n1 = (k1 < 64) ? __shfl(sp, k1) : sb[start + k1];
      a0 += bf2f(fT[((size_t)(b*NP + n0))*64 + lane]);
      a1 += bf2f(fT[((size_t)(b*NP + n1))*64 + lane]);
    }
    if (j < ci){
      int k0 = rel + j;
      int n0 = (k0 < 64) ? __shfl(sp, k0) : sb[start + k0];
      a0 += bf2f(fT[((size_t)(b*NP + n0))*64 + lane]);
    }
    float acc = a0 + a1;
    grid[((size_t)(base + i))*64 + lane] = f2bf(acc / (float)max(ci, 1));
  }
}

// weight pack for 16x16x32 path (point-branch GEMM)
__global__ void k_wprep(const void* __restrict__ w, u16* __restrict__ wfrag, const int* __restrict__ dflag){
  int idx = blockIdx.x; int lane = threadIdx.x;
  int isbf = *dflag;
  int ntl = idx & 3; int kk = (idx >> 2) & 1; int tap = idx >> 3;
  int lh = lane & 15, quad = lane >> 4;
  int n = ntl*16 + lh;
  u16* dst = wfrag + ((size_t)idx*64 + lane)*8;
  for (int j = 0; j < 8; j++){
    int k = kk*32 + quad*8 + j;
    dst[j] = f2bf(ldf(w, (size_t)(tap*64 + k)*64 + n, isbf));
  }
}

// weight pack for 32x32x16 conv path.
// frag idx = (tap*4 + ks)*2 + nh ; B-frag layout: n = lane&31 (cout within 32),
// k = (lane>>5)*8 + j, cin = ks*16 + k.  216 frags x 1 KB = 216 KB (same footprint).
__global__ void k_wprep32(const void* __restrict__ w, u16* __restrict__ wfrag, const int* __restrict__ dflag){
  int idx = blockIdx.x; int lane = threadIdx.x;
  int isbf = *dflag;
  int nh = idx & 1; int ks = (idx >> 1) & 3; int tap = idx >> 3;
  int n = nh*32 + (lane & 31);
  int khalf = lane >> 5;
  u16* dst = wfrag + ((size_t)idx*64 + lane)*8;
  for (int j = 0; j < 8; j++){
    int cin = ks*16 + khalf*8 + j;
    dst[j] = f2bf(ldf(w, (size_t)(tap*64 + cin)*64 + n, isbf));
  }
}

// ---------------- BN helper on spread stats ----------------
__device__ __forceinline__ void bn_params(const float* __restrict__ spread, int c, float invM,
                                          float* mean, float* rs){
  float su = 0.f, sq = 0.f;
  #pragma unroll
  for (int i = 0; i < 8; i++){ su += spread[i*128 + c]; sq += spread[i*128 + 64 + c]; }
  float m = su * invM;
  *mean = m;
  *rs = rsqrtf(sq*invM - m*m + 1e-4f);
}

// ---------------- conv3d 3x3x3, 32x32x16 MFMA, 4u x 4v megatile, fenced pipeline ----------------
// R7: R6 post-mortem showed the L1/VMEM return path is the binding constraint
// (doubling W loads cost +13us despite halving LDS reads). This version reduces
// W bytes per MFMA 2x vs R5 while keeping LDS bytes/MFMA unchanged:
// block = 512 threads (8 waves) covering 4u x 4v output rows; wave = (vsel, nh)
// owns 4 u-rows x 32 couts. Per tap per wave: 16 A ds_reads + 4 W loads -> 16
// MFMAs (W reuse 4x). LDS: 36 halo rows (6u x 6v) x 34 w-slots x 64ch = 153 KB
// (gfx950 has 160 KB/CU; 1 block/CU, 8 waves = 2/SIMD = same as before).
// Per-CU per conv: MFMA 55k cyc, LDS ~65k, W-L1 27k (was 108k in R5).
// Pipeline: W ring 3 banks 2 taps ahead (vmcnt 8); A double-bank 1 half-tap
// ahead (8 ds_reads, lgkmcnt 8); sched_barrier(0) fences; static bank names.
#define ISSUE_W(BANK, TAP) do { \
  _Pragma("unroll") \
  for (int ks_ = 0; ks_ < 4; ks_++) \
    BANK[ks_] = *(const bf8*)(wstream + (size_t)((TAP)*4 + ks_)*1024); \
} while(0)

// A for rows uo = 2H, 2H+1 of tap TAP: 8 ds_read_b128
#define ISSUE_A8(BANK, TAP, H) do { \
  const int t_ = (TAP); \
  const int dwi_ = t_ % 3, dvi_ = (t_/3) % 3, dui_ = t_/9; \
  const u16* rp0_ = &lds_in[((2*(H) + dui_)*6 + vsel + dvi_)*2176]; \
  const u16* rp1_ = rp0_ + 6*2176; \
  const int wp_ = mlane + dwi_; \
  const int wb_ = wp_*64, wx_ = wp_ & 7; \
  _Pragma("unroll") \
  for (int ks_ = 0; ks_ < 4; ks_++){ \
    const int off_ = wb_ + ((((ks_*2) + khalf) ^ wx_) << 3); \
    BANK[ks_]     = *(const bf8*)(rp0_ + off_); \
    BANK[4 + ks_] = *(const bf8*)(rp1_ + off_); \
  } \
} while(0)

#define CONSUME(BW, BA, ACC0, ACC1) do { \
  _Pragma("unroll") \
  for (int ks_ = 0; ks_ < 4; ks_++){ \
    ACC0 = MFMA32(BA[ks_],     BW[ks_], ACC0); \
    ACC1 = MFMA32(BA[4 + ks_], BW[ks_], ACC1); \
  } \
} while(0)

template<int BN>
__global__ __launch_bounds__(512, 1) void k_conv_t(const u16* __restrict__ in, const u16* __restrict__ wfrag,
                                                   u16* __restrict__ out, const float* __restrict__ spread,
                                                   const void* __restrict__ gamma, const void* __restrict__ beta,
                                                   const int* __restrict__ dflag){
  __shared__ u16 lds_in[36*2176];        // 153 KB
  __shared__ float bnA[64], bnB[64];
  int bx = blockIdx.x;
  int b = bx >> 6; int r = bx & 63;
  int u0 = (r >> 3) * 4; int v0 = (r & 7) * 4;
  int tid = threadIdx.x, wv = tid >> 6, lane = tid & 63;

  if constexpr (BN){
    if (tid < 64){
      int isbf = *dflag;
      float mean, rs;
      bn_params(spread, tid, 1.0f/(NB*R3), &mean, &rs);
      float ga = ldf(gamma, tid, isbf), be = ldf(beta, tid, isbf);
      float A = ga*rs;
      bnA[tid] = A; bnB[tid] = be - mean*A;
    }
    __syncthreads();
  }

  uint4 zz; zz.x = 0; zz.y = 0; zz.z = 0; zz.w = 0;
  for (int ri = wv; ri < 36; ri += 8){
    int u2 = u0 + (ri / 6) - 1;
    int v2 = v0 + (ri % 6) - 1;
    uint4* dstrow = (uint4*)&lds_in[ri*2176];
    if ((unsigned)u2 > 31u || (unsigned)v2 > 31u){
      for (int i = lane; i < 272; i += 64) dstrow[i] = zz;
      continue;
    }
    const uint4* src = (const uint4*)(in + ((size_t)(b*R3 + (u2*32 + v2)*32))*64);
    if (lane < 8) dstrow[lane] = zz;
    else if (lane < 16) dstrow[264 + (lane & 7)] = zz;
    #pragma unroll
    for (int ch = 0; ch < 4; ch++){
      int idx = ch*64 + lane;
      int w = idx >> 3, cc = idx & 7;
      uint4 v = src[idx];
      if constexpr (BN){
        u32 in4[4] = {v.x, v.y, v.z, v.w};
        u32 o4[4];
        #pragma unroll
        for (int k = 0; k < 4; k++){
          int c = cc*8 + 2*k;
          float lo = u2f(in4[k] << 16);
          float hi = u2f(in4[k] & 0xFFFF0000u);
          lo = bnA[c]*lo + bnB[c];     lo = (lo >= 0.f) ? lo : 0.1f*lo;
          hi = bnA[c+1]*hi + bnB[c+1]; hi = (hi >= 0.f) ? hi : 0.1f*hi;
          o4[k] = (u32)f2bf(lo) | ((u32)f2bf(hi) << 16);
        }
        v.x = o4[0]; v.y = o4[1]; v.z = o4[2]; v.w = o4[3];
      }
      int wp = w + 1;
      dstrow[wp*8 + (cc ^ (wp & 7))] = v;
    }
  }
  __syncthreads();

  int vsel = wv & 3, nh = wv >> 2;
  int v_i = v0 + vsel;
  int mlane = lane & 31;          // output w position (M dim)
  int khalf = lane >> 5;          // k-half within a K=16 step
  f16x acc0, acc1, acc2, acc3;    // u-rows u0+0..3
  #pragma unroll
  for (int i = 0; i < 16; i++){ acc0[i] = 0.f; acc1[i] = 0.f; acc2[i] = 0.f; acc3[i] = 0.f; }

  const u16* wstream = wfrag + (size_t)nh*512 + (size_t)lane*8;  // + (tap*4+ks)*1024 per frag

  bf8 W0[4], W1[4], W2[4];        // weight ring, 2 taps ahead
  bf8 Aa[8], Ab[8];               // A double-bank, 1 half-tap ahead (2 rows each)

  ISSUE_W(W0, 0);
  ISSUE_W(W1, 1);
  ISSUE_A8(Aa, 0, 0);

  #pragma unroll
  for (int tap = 0; tap < 27; ++tap){
    const int pf = tap + 2;
    if (pf < 27){
      if (pf % 3 == 0)      ISSUE_W(W0, pf);
      else if (pf % 3 == 1) ISSUE_W(W1, pf);
      else                  ISSUE_W(W2, pf);
    }
    // ---- half 0: rows u0+0, u0+1 (bank Aa); prefetch half 1 into Ab
    ISSUE_A8(Ab, tap, 1);
    __builtin_amdgcn_sched_barrier(0);
    if (tap < 25)       asm volatile("s_waitcnt vmcnt(8) lgkmcnt(8)");
    else if (tap == 25) asm volatile("s_waitcnt vmcnt(4) lgkmcnt(8)");
    else                asm volatile("s_waitcnt vmcnt(0) lgkmcnt(8)");
    __builtin_amdgcn_sched_barrier(0);
    {
      const int wsel = tap % 3;
      if (wsel == 0)      CONSUME(W0, Aa, acc0, acc1);
      else if (wsel == 1) CONSUME(W1, Aa, acc0, acc1);
      else                CONSUME(W2, Aa, acc0, acc1);
    }
    // ---- half 1: rows u0+2, u0+3 (bank Ab); prefetch next tap half 0 into Aa
    if (tap + 1 < 27) ISSUE_A8(Aa, tap + 1, 0);
    __builtin_amdgcn_sched_barrier(0);
    if (tap < 25)       asm volatile("s_waitcnt vmcnt(8) lgkmcnt(8)");
    else if (tap == 25) asm volatile("s_waitcnt vmcnt(4) lgkmcnt(8)");
    else                asm volatile("s_waitcnt vmcnt(0) lgkmcnt(0)");
    __builtin_amdgcn_sched_barrier(0);
    {
      const int wsel = tap % 3;
      if (wsel == 0)      CONSUME(W0, Ab, acc2, acc3);
      else if (wsel == 1) CONSUME(W1, Ab, acc2, acc3);
      else                CONSUME(W2, Ab, acc2, acc3);
    }
  }

  // C/D layout 32x32: col = lane&31 (cout), row = (reg&3) + 8*(reg>>2) + 4*(lane>>5)
  int co = nh*32 + mlane;
  int rbase = 4*khalf;
  size_t base0 = ((size_t)(b*R3 + ((u0+0)*32 + v_i)*32))*64;
  size_t base1 = ((size_t)(b*R3 + ((u0+1)*32 + v_i)*32))*64;
  size_t base2 = ((size_t)(b*R3 + ((u0+2)*32 + v_i)*32))*64;
  size_t base3 = ((size_t)(b*R3 + ((u0+3)*32 + v_i)*32))*64;
  #pragma unroll
  for (int reg = 0; reg < 16; reg++){
    int row = (reg & 3) + 8*(reg >> 2) + rbase;       // w position
    out[base0 + (size_t)row*64 + co] = f2bf(acc0[reg]);
    out[base1 + (size_t)row*64 + co] = f2bf(acc1[reg]);
    out[base2 + (size_t)row*64 + co] = f2bf(acc2[reg]);
    out[base3 + (size_t)row*64 + co] = f2bf(acc3[reg]);
  }
}

// ---------------- fast channel stats ----------------
__global__ __launch_bounds__(256) void k_stats2(const u16* __restrict__ buf, float* __restrict__ spread, int M){
  __shared__ float sred[4*128];
  int tid = threadIdx.x, bx = blockIdx.x;
  int wv = tid >> 6, lane = tid & 63;
  int sub = lane & 7;
  int g = bx*256 + tid;
  float s[8], s2[8];
  #pragma unroll
  for (int j = 0; j < 8; j++){ s[j] = 0.f; s2[j] = 0.f; }
  const uint4* p4 = (const uint4*)buf;
  size_t total = (size_t)M * 8;
  for (size_t f = g; f < total; f += 262144){
    uint4 v = p4[f];
    u32 ws_[4] = {v.x, v.y, v.z, v.w};
    #pragma unroll
    for (int k = 0; k < 4; k++){
      float lo = u2f(ws_[k] << 16);
      float hi = u2f(ws_[k] & 0xFFFF0000u);
      s[2*k]   += lo; s2[2*k]   += lo*lo;
      s[2*k+1] += hi; s2[2*k+1] += hi*hi;
    }
  }
  #pragma unroll
  for (int j = 0; j < 8; j++){
    #pragma unroll
    for (int m = 8; m <= 32; m <<= 1){
      s[j]  += __shfl_xor(s[j],  m);
      s2[j] += __shfl_xor(s2[j], m);
    }
  }
  if (lane < 8){
    #pragma unroll
    for (int j = 0; j < 8; j++){
      sred[wv*128 + sub*8 + j]      = s[j];
      sred[wv*128 + 64 + sub*8 + j] = s2[j];
    }
  }
  __syncthreads();
  if (tid < 128){
    float t = sred[tid] + sred[128+tid] + sred[256+tid] + sred[384+tid];
    atomicAdd(&spread[(bx & 7)*128 + tid], t);
  }
}

__global__ void k_ftrans(const void* __restrict__ feat, u16* __restrict__ fT, const int* __restrict__ dflag){
  __shared__ u16 t[64*65];
  int bx = blockIdx.x;
  int isbf = *dflag;
  int b = bx >> 8; int n0 = (bx & 255) * 64;
  int tid = threadIdx.x;
  int nl = tid & 63; int cq = tid >> 6;
  for (int cp = 0; cp < 16; cp++){
    int c = cq + cp*4;
    t[c*65 + nl] = f2bf(ldf(feat, ((size_t)(b*NCH + c))*NP + n0 + nl, isbf));
  }
  __syncthreads();
  for (int np2 = 0; np2 < 16; np2++){
    int n = np2*4 + cq; int c = nl;
    fT[((size_t)(b*NP + n0 + n))*64 + c] = t[c*65 + n];
  }
}

__global__ void k_pgemm(const u16* __restrict__ fT, const u16* __restrict__ wfp, u16* __restrict__ p){
  __shared__ u16 As[128*64];
  int bx = blockIdx.x;
  size_t row0 = (size_t)bx * 128;
  int tid = threadIdx.x, wv = tid >> 6, lane = tid & 63;
  const uint4* src = (const uint4*)(fT + row0*64);
  uint4* dst = (uint4*)As;
  for (int i = tid; i < 1024; i += 256) dst[i] = src[i];
  __syncthreads();
  int lh = lane & 15, quad = lane >> 4;
  f4 z4 = {0.f,0.f,0.f,0.f};
  f4 acc[2][4];
  for (int i = 0; i < 2; i++) for (int j = 0; j < 4; j++) acc[i][j] = z4;
  const u16* ap = &As[(wv*32)*64];
  #pragma unroll
  for (int kk = 0; kk < 2; kk++){
    bf8 a0 = *(const bf8*)(ap + lh*64 + kk*32 + quad*8);
    bf8 a1 = *(const bf8*)(ap + (16+lh)*64 + kk*32 + quad*8);
    #pragma unroll
    for (int ntl = 0; ntl < 4; ntl++){
      bf8 bf = *(const bf8*)(wfp + ((size_t)(kk*4 + ntl)*64 + lane)*8);
      acc[0][ntl] = MFMA(a0, bf, acc[0][ntl]);
      acc[1][ntl] = MFMA(a1, bf, acc[1][ntl]);
    }
  }
  #pragma unroll
  for (int mt = 0; mt < 2; mt++)
    for (int ntl = 0; ntl < 4; ntl++)
      for (int reg = 0; reg < 4; reg++){
        int rr = wv*32 + mt*16 + quad*4 + reg;
        p[(row0 + rr)*64 + ntl*16 + lh] = f2bf(acc[mt][ntl][reg]);
      }
}

// devox with BN2+LeakyReLU fused on the grid gathers + point-branch BN
__global__ void k_devox(const u16* __restrict__ grid, const u16* __restrict__ p,
                        const float* __restrict__ stP, const float* __restrict__ st2,
                        const void* __restrict__ pfg, const void* __restrict__ pfb,
                        const void* __restrict__ g2, const void* __restrict__ b2,
                        const float* __restrict__ nc, void* __restrict__ out0,
                        const int* __restrict__ dflag){
  __shared__ float t[64*65];
  int bx = blockIdx.x;
  int isbf = *dflag;
  int b = bx >> 8; int n0 = (bx & 255) * 64;
  int tid = threadIdx.x, wv = tid >> 6, lane = tid & 63;
  int c = lane;
  float meanP, rsP;
  bn_params(stP, c, 1.0f/(NB*NP), &meanP, &rsP);
  float gaP = ldf(pfg, c, isbf), beP = ldf(pfb, c, isbf);
  float mean2, rs2;
  bn_params(st2, c, 1.0f/(NB*R3), &mean2, &rs2);
  float ga2 = ldf(g2, c, isbf), be2 = ldf(b2, c, isbf);
  float A2 = ga2*rs2, B2 = be2 - mean2*A2;
  for (int pt = wv; pt < 64; pt += 4){
    int n = n0 + pt;
    float nx = nc[(b*3+0)*NP + n];
    float ny = nc[(b*3+1)*NP + n];
    float nz = nc[(b*3+2)*NP + n];
    float x0f = floorf(nx), y0f = floorf(ny), z0f = floorf(nz);
    int x0 = (int)x0f, y0 = (int)y0f, z0 = (int)z0f;
    float fx = nx - x0f, fy = ny - y0f, fz = nz - z0f;
    int x1 = min(x0+1,31), y1 = min(y0+1,31), z1 = min(z0+1,31);
    float acc = 0.f;
    #pragma unroll
    for (int k = 0; k < 8; k++){
      int dx = k >> 2, dy = (k >> 1) & 1, dz = k & 1;
      int xs = dx ? x1 : x0, ys = dy ? y1 : y0, zs = dz ? z1 : z0;
      float wgt = (dx ? fx : 1.f-fx)*(dy ? fy : 1.f-fy)*(dz ? fz : 1.f-fz);
      float gv = bf2f(grid[((size_t)(b*R3 + (xs*32+ys)*32 + zs))*64 + c]);
      gv = A2*gv + B2;
      gv = (gv >= 0.f) ? gv : 0.1f*gv;
      acc += wgt * gv;
    }
    float pv = bf2f(p[((size_t)(b*NP + n))*64 + c]);
    float y = gaP*(pv - meanP)*rsP + beP;
    y = (y >= 0.f) ? y : 0.1f*y;
    t[pt*65 + c] = acc + y;
  }
  __syncthreads();
  for (int cp = 0; cp < 16; cp++){
    int co = wv + cp*4;
    size_t oi = ((size_t)(b*NCH + co))*NP + n0 + lane;
    float val = t[lane*65 + co];
    if (isbf) ((u16*)out0)[oi] = f2bf(val);
    else      ((float*)out0)[oi] = val;
  }
}

__global__ void k_copycoords(const void* __restrict__ coords, void* __restrict__ out0,
                             const int* __restrict__ dflag){
  int g = blockIdx.x*256 + threadIdx.x;
  int isbf = *dflag;
  size_t oi = (size_t)NB*NCH*NP + g;
  if (isbf) ((u16*)out0)[oi]   = ((const u16*)coords)[g];
  else      ((float*)out0)[oi] = ((const float*)coords)[g];
}

extern "C" void kernel_launch(void* const* d_in, const int* in_sizes, int n_in,
                              void* d_out, int out_size, void* d_ws, size_t ws_size,
                              hipStream_t stream){
  if (ws_size < WS_NEED) return;

  const void* feat   = d_in[0];
  const void* coords = d_in[1];
  const void* w1     = d_in[2];
  const void* g1     = d_in[4];
  const void* b1     = d_in[5];
  const void* w2     = d_in[6];
  const void* g2     = d_in[8];
  const void* b2     = d_in[9];
  const void* pw     = d_in[10];
  const void* pg     = d_in[12];
  const void* pb     = d_in[13];

  char* ws = (char*)d_ws;
  u16*   gridv = (u16*)(ws + OFF_GRID);
  u16*   buf1  = (u16*)(ws + OFF_BUF1);
  u16*   fT    = (u16*)(ws + OFF_FT);     // overlays buf1; dead before conv1 writes
  u16*   p     = (u16*)(ws + OFF_P);
  int*   cnt   = (int*)(ws + OFF_CNT);
  float* small = (float*)(ws + OFF_SMALL);
  int*   dflag = (int*)(small + 448);
  float* stat  = (float*)(ws + OFF_STAT); // [3][1024] spread: conv1 | conv2 | point
  int*   offs  = (int*)(ws + OFF_OFFS);
  float* nc    = (float*)(ws + OFF_NC);
  int*   vidx  = (int*)(ws + OFF_VIDX);
  int*   sorted= (int*)(ws + OFF_SORT);
  u16*   wf1   = (u16*)(ws + OFF_WF1);
  u16*   wf2   = (u16*)(ws + OFF_WF2);
  u16*   wfp   = (u16*)(ws + OFF_WFP);

  hipMemsetAsync(ws + ZOFF, 0, ZBYTES, stream);
  k_dtype<<<1, 64, 0, stream>>>((const uint32_t*)g1, dflag);

  k_wprep32<<<27*8, 64, 0, stream>>>(w1, wf1, dflag);
  k_wprep32<<<27*8, 64, 0, stream>>>(w2, wf2, dflag);
  k_wprep<<<8, 64, 0, stream>>>(pw, wfp, dflag);

  k_coordstats<<<NB, 1024, 0, stream>>>(coords, small, dflag);
  k_pointprep<<<NB*NP/256, 256, 0, stream>>>(coords, small, nc, vidx, cnt, dflag);
  k_scan<<<NB, 1024, 0, stream>>>(cnt, offs);
  k_sortpts<<<NB*NP/256, 256, 0, stream>>>(vidx, offs, sorted);

  k_ftrans<<<NB*NP/64, 256, 0, stream>>>(feat, fT, dflag);
  k_voxsum<<<NB*R3/64, 256, 0, stream>>>(fT, sorted, cnt, offs, gridv);
  k_pgemm<<<NB*NP/128, 256, 0, stream>>>(fT, wfp, p);
  k_stats2<<<1024, 256, 0, stream>>>(p, stat + 2048, NB*NP);

  k_conv_t<0><<<NB*64, 512, 0, stream>>>(gridv, wf1, buf1, nullptr, nullptr, nullptr, nullptr);
  k_stats2<<<1024, 256, 0, stream>>>(buf1, stat + 0, NB*R3);

  k_conv_t<1><<<NB*64, 512, 0, stream>>>(buf1, wf2, gridv, stat + 0, g1, b1, dflag);
  k_stats2<<<1024, 256, 0, stream>>>(gridv, stat + 1024, NB*R3);

  k_devox<<<NB*NP/64, 256, 0, stream>>>(gridv, p, stat + 2048, stat + 1024,
                                        pg, pb, g2, b2, nc, d_out, dflag);
  k_copycoords<<<NB*3*NP/256, 256, 0, stream>>>(coords, d_out, dflag);
}